// Round 5
// baseline (48.099 us; speedup 1.0000x reference)
//
#include <hip/hip_runtime.h>
#include <math.h>

// StructLoss: sqrt(mean(|grads4(outputs - labels)|) + 1e-16)
// grads4 linear -> compute on d = outputs - labels.
// [B=16, C=6, H=512, W=512] fp32; mean over B*4C*H*W.
//
// Block = one 8x512 tile. Stage RAW outputs+labels halo tiles (10 rows each)
// into LDS via global_load_lds 16B DMA (no VGPR round-trip; ~40KB in flight
// per block). Subtract on consume. Halo rows: clamped DMA address + 0/1 mask
// multiply at read. Compute: per-wave 2-row rolling window, shfl col edges.

#define NTHREADS 256
#define TROWS 8
#define SROWS (TROWS + 2)                  // 10 staged rows
#define WV 512
#define HT 512
#define PLANES 96
#define STRIPS (HT / TROWS)                // 64
#define NBLOCKS (PLANES * STRIPS)          // 6144
#define TILE_F (SROWS * WV)                // 5120 floats per array
#define CHUNKS (2 * SROWS * 2)             // 40 x 1KB chunks (2 arrays)
#define CHUNKS_PER_WAVE (CHUNKS / 4)       // 10

__device__ __forceinline__ void gload_lds16(const float* g, float* l) {
    __builtin_amdgcn_global_load_lds(
        (const __attribute__((address_space(1))) void*)g,
        (__attribute__((address_space(3))) void*)l, 16, 0, 0);
}

struct Row { float d[8]; float eL, eR; };

// Read one staged row: d = mask * (out - lab). Shfl for column neighbors.
__device__ __forceinline__ Row lds_row(const float* __restrict__ sd,
                                       int sr, int lane, float m) {
    const float4 a  = *reinterpret_cast<const float4*>(sd + sr * WV + lane * 8);
    const float4 b  = *reinterpret_cast<const float4*>(sd + sr * WV + lane * 8 + 4);
    const float4 c  = *reinterpret_cast<const float4*>(sd + TILE_F + sr * WV + lane * 8);
    const float4 dd = *reinterpret_cast<const float4*>(sd + TILE_F + sr * WV + lane * 8 + 4);
    Row row;
    row.d[0] = m * (a.x - c.x);  row.d[1] = m * (a.y - c.y);
    row.d[2] = m * (a.z - c.z);  row.d[3] = m * (a.w - c.w);
    row.d[4] = m * (b.x - dd.x); row.d[5] = m * (b.y - dd.y);
    row.d[6] = m * (b.z - dd.z); row.d[7] = m * (b.w - dd.w);
    const float up = __shfl_up(row.d[7], 1, 64);
    const float dn = __shfl_down(row.d[0], 1, 64);
    row.eL = (lane == 0)  ? 0.f : up;   // col 8l-1 (image zero-pad)
    row.eR = (lane == 63) ? 0.f : dn;   // col 8l+8 (image zero-pad)
    return row;
}

__global__ __launch_bounds__(NTHREADS) void struct_loss_partial(
        const float* __restrict__ out_p, const float* __restrict__ lab_p,
        float* __restrict__ partials) {
    __shared__ float sd[2 * TILE_F];           // 40,960 B

    const int plane = blockIdx.x >> 6;         // / STRIPS
    const int strip = blockIdx.x & (STRIPS - 1);
    const int row0  = strip * TROWS;
    const size_t pbase = (size_t)plane * (HT * WV);

    const int wid  = threadIdx.x >> 6;
    const int lane = threadIdx.x & 63;

    // ---- stage: async DMA, 10 x 1KB chunks per wave, no VGPR round-trip ----
    #pragma unroll
    for (int k = 0; k < CHUNKS_PER_WAVE; ++k) {
        const int c   = wid * CHUNKS_PER_WAVE + k;   // 0..39
        const int arr = (c >= CHUNKS / 2) ? 1 : 0;   // 0:outputs 1:labels
        const int cc  = c - (CHUNKS / 2) * arr;      // 0..19
        const int r   = cc >> 1;                     // staged row 0..9
        const int h   = cc & 1;                      // half-row
        const int gr  = min(max(row0 + r - 1, 0), HT - 1);   // clamped addr
        const float* src = (arr ? lab_p : out_p) + pbase
                         + (size_t)gr * WV + h * 256 + lane * 4;
        gload_lds16(src, sd + c * 256);              // wave-uniform LDS base
    }
    __syncthreads();                                 // drains vmcnt (DMA done)

    // ---- compute: wave w owns tile rows 2w..2w+1 (staged rows 2w..2w+3) ----
    float acc = 0.f;
    {
        const int sr0 = wid * 2;
        const float m0 = ((unsigned)(row0 + sr0 - 1) < (unsigned)HT) ? 1.f : 0.f;
        Row rp = lds_row(sd, sr0,     lane, m0);
        Row rc = lds_row(sd, sr0 + 1, lane, 1.f);    // always interior
        #pragma unroll
        for (int rr = 0; rr < 2; ++rr) {
            const int sr = sr0 + 2 + rr;
            const float mn = ((unsigned)(row0 + sr - 1) < (unsigned)HT) ? 1.f : 0.f;
            Row rn = lds_row(sd, sr, lane, mn);

            #pragma unroll
            for (int k = 0; k < 8; ++k) {
                const float cL = (k > 0) ? rc.d[k - 1] : rc.eL;
                const float cR = (k < 7) ? rc.d[k + 1] : rc.eR;
                const float pL = (k > 0) ? rp.d[k - 1] : rp.eL;
                const float pR = (k < 7) ? rp.d[k + 1] : rp.eR;
                const float nL = (k > 0) ? rn.d[k - 1] : rn.eL;
                const float nR = (k < 7) ? rn.d[k + 1] : rn.eR;

                const float gy = rp.d[k] - rn.d[k];   // x[i-1,j]   - x[i+1,j]
                const float gx = cL - cR;             // x[i,j-1]   - x[i,j+1]
                const float gD = pL - nR;             // x[i-1,j-1] - x[i+1,j+1]
                const float gd = pR - nL;             // x[i-1,j+1] - x[i+1,j-1]
                acc += fabsf(gy) + fabsf(gx) + fabsf(gD) + fabsf(gd);
            }
            rp = rc;
            rc = rn;
        }
    }

    // ---- block reduction ----
    #pragma unroll
    for (int off = 32; off > 0; off >>= 1)
        acc += __shfl_down(acc, off, 64);

    __shared__ float smem[NTHREADS / 64];
    if (lane == 0) smem[wid] = acc;
    __syncthreads();
    if (threadIdx.x == 0) {
        float s = 0.f;
        #pragma unroll
        for (int w = 0; w < NTHREADS / 64; ++w) s += smem[w];
        partials[blockIdx.x] = s;
    }
}

__global__ __launch_bounds__(256) void struct_loss_final(
        const float* __restrict__ partial, float* __restrict__ out,
        int nparts, double inv_count) {
    double acc = 0.0;
    for (int i = threadIdx.x; i < nparts; i += blockDim.x)
        acc += (double)partial[i];
    #pragma unroll
    for (int off = 32; off > 0; off >>= 1)
        acc += __shfl_down(acc, off, 64);
    __shared__ double smem[4];
    const int lane = threadIdx.x & 63;
    const int wid  = threadIdx.x >> 6;
    if (lane == 0) smem[wid] = acc;
    __syncthreads();
    if (threadIdx.x == 0) {
        double s = smem[0] + smem[1] + smem[2] + smem[3];
        out[0] = (float)sqrt(s * inv_count + 1e-16);
    }
}

extern "C" void kernel_launch(void* const* d_in, const int* in_sizes, int n_in,
                              void* d_out, int out_size, void* d_ws, size_t ws_size,
                              hipStream_t stream) {
    const float* outputs = (const float*)d_in[0];
    const float* labels  = (const float*)d_in[1];
    float* out = (float*)d_out;
    float* partials = (float*)d_ws;   // NBLOCKS floats

    const double inv_count = 1.0 / (16.0 * 24.0 * 512.0 * 512.0);

    struct_loss_partial<<<NBLOCKS, NTHREADS, 0, stream>>>(outputs, labels, partials);
    struct_loss_final<<<1, 256, 0, stream>>>(partials, out, NBLOCKS, inv_count);
}

// Round 6
// 40.161 us; speedup vs baseline: 1.1977x; 1.1977x over previous
//
#include <hip/hip_runtime.h>
#include <math.h>

// StructLoss: sqrt(mean(|grads4(outputs - labels)|) + 1e-16)
// grads4 linear -> compute on d = outputs - labels.
// [B=16, C=6, H=512, W=512] fp32; mean over B*4C*H*W.
//
// Persistent software pipeline: 768 blocks (3/CU exactly), each owns 4
// consecutive 16-row strips. While computing strip t from LDS, the raw
// halo tile of strip t+1 (18 rows x 2 arrays) is register-staged via
// unconditional clamped float4 loads (issued early, pinned by
// sched_barrier). Subtract + zero-pad mask applied at ds_write.
// Compute: per-wave 4-row rolling window, shfl column edges.

#define NTHREADS 256
#define TROWS 16
#define SROWS (TROWS + 2)                        // 18 staged rows
#define WV 512
#define HT 512
#define PLANES 96
#define STRIPS_PER_PLANE (HT / TROWS)            // 32
#define TOTAL_STRIPS (PLANES * STRIPS_PER_PLANE) // 3072
#define SPB 4                                    // strips per block
#define NBLOCKS (TOTAL_STRIPS / SPB)             // 768 = 3 blocks/CU exactly
#define LDK 9                                    // float4 per thread per array

struct Row { float d[8]; float eL, eR; };

__device__ __forceinline__ Row lds_row(const float* __restrict__ sd,
                                       int sr, int lane) {
    Row row;
    const float4 a = *reinterpret_cast<const float4*>(sd + sr * WV + lane * 8);
    const float4 b = *reinterpret_cast<const float4*>(sd + sr * WV + lane * 8 + 4);
    row.d[0] = a.x; row.d[1] = a.y; row.d[2] = a.z; row.d[3] = a.w;
    row.d[4] = b.x; row.d[5] = b.y; row.d[6] = b.z; row.d[7] = b.w;
    const float up = __shfl_up(row.d[7], 1, 64);
    const float dn = __shfl_down(row.d[0], 1, 64);
    row.eL = (lane == 0)  ? 0.f : up;   // col 8l-1 (image zero-pad)
    row.eR = (lane == 63) ? 0.f : dn;   // col 8l+8 (image zero-pad)
    return row;
}

__device__ __forceinline__ void issue_loads(const float* __restrict__ out_p,
                                            const float* __restrict__ lab_p,
                                            int s, int tid,
                                            float4 (&ov)[LDK], float4 (&lv)[LDK]) {
    const int plane = s >> 5;                    // / STRIPS_PER_PLANE
    const int row0  = (s & 31) * TROWS;
    const size_t pbase = (size_t)plane * (HT * WV);
    #pragma unroll
    for (int k = 0; k < LDK; ++k) {
        const int p  = tid + NTHREADS * k;       // float4 slot 0..2303
        const int r  = p >> 7;                   // staged row 0..17
        const int c4 = p & 127;
        const int gr = min(max(row0 + r - 1, 0), HT - 1);  // clamp: always valid
        const size_t goff = pbase + (size_t)gr * WV + c4 * 4;
        ov[k] = *reinterpret_cast<const float4*>(out_p + goff);
        lv[k] = *reinterpret_cast<const float4*>(lab_p + goff);
    }
}

__device__ __forceinline__ void write_tile(float* __restrict__ sd, int s, int tid,
                                           const float4 (&ov)[LDK],
                                           const float4 (&lv)[LDK]) {
    const int row0 = (s & 31) * TROWS;
    #pragma unroll
    for (int k = 0; k < LDK; ++k) {
        const int p = tid + NTHREADS * k;
        const int r = p >> 7;
        const int gr = row0 + r - 1;
        const float m = ((unsigned)gr < (unsigned)HT) ? 1.f : 0.f;  // zero-pad halo
        float4 d;
        d.x = m * (ov[k].x - lv[k].x);
        d.y = m * (ov[k].y - lv[k].y);
        d.z = m * (ov[k].z - lv[k].z);
        d.w = m * (ov[k].w - lv[k].w);
        *reinterpret_cast<float4*>(sd + (size_t)p * 4) = d;
    }
}

__device__ __forceinline__ float compute_tile(const float* __restrict__ sd,
                                              int wid, int lane) {
    float acc = 0.f;
    const int sr0 = wid * 4;                     // wave owns tile rows 4w..4w+3
    Row rp = lds_row(sd, sr0,     lane);
    Row rc = lds_row(sd, sr0 + 1, lane);
    #pragma unroll
    for (int rr = 0; rr < 4; ++rr) {
        Row rn = lds_row(sd, sr0 + 2 + rr, lane);
        #pragma unroll
        for (int k = 0; k < 8; ++k) {
            const float cL = (k > 0) ? rc.d[k - 1] : rc.eL;
            const float cR = (k < 7) ? rc.d[k + 1] : rc.eR;
            const float pL = (k > 0) ? rp.d[k - 1] : rp.eL;
            const float pR = (k < 7) ? rp.d[k + 1] : rp.eR;
            const float nL = (k > 0) ? rn.d[k - 1] : rn.eL;
            const float nR = (k < 7) ? rn.d[k + 1] : rn.eR;

            const float gy = rp.d[k] - rn.d[k];   // x[i-1,j]   - x[i+1,j]
            const float gx = cL - cR;             // x[i,j-1]   - x[i,j+1]
            const float gD = pL - nR;             // x[i-1,j-1] - x[i+1,j+1]
            const float gd = pR - nL;             // x[i-1,j+1] - x[i+1,j-1]
            acc += fabsf(gy) + fabsf(gx) + fabsf(gD) + fabsf(gd);
        }
        rp = rc;
        rc = rn;
    }
    return acc;
}

__global__ __launch_bounds__(NTHREADS) void struct_loss_partial(
        const float* __restrict__ out_p, const float* __restrict__ lab_p,
        float* __restrict__ partials) {
    __shared__ float sd[SROWS * WV];             // 36,864 B

    const int tid  = threadIdx.x;
    const int wid  = tid >> 6;
    const int lane = tid & 63;
    const int s0   = blockIdx.x * SPB;           // 4 consecutive strips

    float acc = 0.f;
    float4 ov[LDK], lv[LDK];

    // Prologue: stage strip 0 (latency exposed once per block).
    issue_loads(out_p, lab_p, s0, tid, ov, lv);
    __builtin_amdgcn_sched_barrier(0);
    write_tile(sd, s0, tid, ov, lv);
    __syncthreads();

    #pragma unroll
    for (int t = 0; t < SPB; ++t) {
        // Issue next strip's loads BEFORE computing current (latency hides
        // under compute). Fully unrolled -> guards are compile-time.
        if (t + 1 < SPB) {
            issue_loads(out_p, lab_p, s0 + t + 1, tid, ov, lv);
            __builtin_amdgcn_sched_barrier(0);
        }
        acc += compute_tile(sd, wid, lane);
        __syncthreads();                         // all waves done reading sd
        if (t + 1 < SPB) {
            write_tile(sd, s0 + t + 1, tid, ov, lv);  // waits vmcnt via dep
            __syncthreads();                     // writes visible
        }
    }

    // ---- block reduction ----
    #pragma unroll
    for (int off = 32; off > 0; off >>= 1)
        acc += __shfl_down(acc, off, 64);

    __shared__ float smem[NTHREADS / 64];
    if (lane == 0) smem[wid] = acc;
    __syncthreads();
    if (tid == 0) {
        float s = 0.f;
        #pragma unroll
        for (int w = 0; w < NTHREADS / 64; ++w) s += smem[w];
        partials[blockIdx.x] = s;
    }
}

__global__ __launch_bounds__(256) void struct_loss_final(
        const float* __restrict__ partial, float* __restrict__ out,
        int nparts, double inv_count) {
    double acc = 0.0;
    for (int i = threadIdx.x; i < nparts; i += blockDim.x)
        acc += (double)partial[i];
    #pragma unroll
    for (int off = 32; off > 0; off >>= 1)
        acc += __shfl_down(acc, off, 64);
    __shared__ double smem[4];
    const int lane = threadIdx.x & 63;
    const int wid  = threadIdx.x >> 6;
    if (lane == 0) smem[wid] = acc;
    __syncthreads();
    if (threadIdx.x == 0) {
        double s = smem[0] + smem[1] + smem[2] + smem[3];
        out[0] = (float)sqrt(s * inv_count + 1e-16);
    }
}

extern "C" void kernel_launch(void* const* d_in, const int* in_sizes, int n_in,
                              void* d_out, int out_size, void* d_ws, size_t ws_size,
                              hipStream_t stream) {
    const float* outputs = (const float*)d_in[0];
    const float* labels  = (const float*)d_in[1];
    float* out = (float*)d_out;
    float* partials = (float*)d_ws;   // NBLOCKS floats

    const double inv_count = 1.0 / (16.0 * 24.0 * 512.0 * 512.0);

    struct_loss_partial<<<NBLOCKS, NTHREADS, 0, stream>>>(outputs, labels, partials);
    struct_loss_final<<<1, 256, 0, stream>>>(partials, out, NBLOCKS, inv_count);
}